// Round 3
// baseline (605.940 us; speedup 1.0000x reference)
//
#include <hip/hip_runtime.h>

#define NSEQ   64
#define NHEAD  32
#define KVH    8
#define HS     128
#define BS     16
#define MBPS   64
#define PARTS  16
#define PSIZE  64    // tokens per partition (4 pages, fixed)
#define QPKV   4
#define SCALE_F 0.08838834764831845f

#define O_PART_ELEMS (NSEQ*KVH*PARTS*QPKV*HS)
#define ML_ELEMS     (NSEQ*KVH*PARTS*QPKV)

// One WG per (seq, kv_head, partition of 64 tokens). Wave w = query head w of
// the GQA group; everything is wave-private (no barriers). Always processes
// exactly 4 pages (block table is fully populated; tail masked in softmax)
// -> uniform control flow, fully unrolled, loads batched for MLP.
__launch_bounds__(256, 4)
__global__ void pa_part(const float* __restrict__ q,
                        const float* __restrict__ kc,
                        const float* __restrict__ vc,
                        const int*   __restrict__ bt,
                        const int*   __restrict__ cl,
                        float*       __restrict__ o_part,
                        float*       __restrict__ m_part,
                        float*       __restrict__ l_part)
{
    const int bx   = blockIdx.x;
    const int part = bx & (PARTS - 1);
    const int kvh  = (bx >> 4) & (KVH - 1);
    const int seq  = bx >> 7;
    const int ctx  = cl[seq];
    const int tok0 = part * PSIZE;
    if (tok0 >= ctx) return;
    const int ntok = min(PSIZE, ctx - tok0);

    const int w    = threadIdx.x >> 6;   // query head in GQA group
    const int lane = threadIdx.x & 63;
    const int tok  = lane & 15;          // token within page
    const int dq   = lane >> 4;          // dim quarter [dq*32, +32)

    __shared__ float sc[QPKV][PSIZE];

    // all 4 page IDs up front — one 16B load, no per-iteration scalar chain
    const int4 blkv = *(const int4*)(bt + seq * MBPS + part * 4);
    const int blks[4] = {blkv.x, blkv.y, blkv.z, blkv.w};

    // Q: 32 dims for (head w, quarter dq) in registers
    const float4* qp = (const float4*)(q + ((size_t)seq * NHEAD + kvh * QPKV + w) * HS + dq * 32);
    float4 qv[8];
#pragma unroll
    for (int k = 0; k < 8; ++k) qv[k] = qp[k];

    // ---- Pass 1: scores, 4 pages fully unrolled ----
    // K page layout: [dpart(16)][tok(16)][8] floats. Lane reads 4x32B chunks;
    // each 16-lane group covers a contiguous 512B segment.
    float s[4];
#pragma unroll
    for (int b = 0; b < 4; ++b) {
        const float* kb = kc + ((size_t)blks[b] * KVH + kvh) * (HS * BS)
                             + dq * 4 * (BS * 8) + tok * 8;
        float4 kk[8];
#pragma unroll
        for (int k = 0; k < 4; ++k) {
            kk[2*k]   = ((const float4*)(kb + k * (BS * 8)))[0];
            kk[2*k+1] = ((const float4*)(kb + k * (BS * 8)))[1];
        }
        float acc = 0.f;
#pragma unroll
        for (int k = 0; k < 8; ++k)
            acc += qv[k].x*kk[k].x + qv[k].y*kk[k].y + qv[k].z*kk[k].z + qv[k].w*kk[k].w;
        s[b] = acc;
    }
#pragma unroll
    for (int b = 0; b < 4; ++b) {
        s[b] += __shfl_xor(s[b], 16);
        s[b] += __shfl_xor(s[b], 32);
    }
    if (lane < 16) {
#pragma unroll
        for (int b = 0; b < 4; ++b)
            sc[w][b * BS + tok] = s[b] * SCALE_F;
    }

    // ---- wave-private softmax: one token per lane (PSIZE == 64) ----
    const float sv    = sc[w][lane];
    const bool  valid = lane < ntok;
    float m = valid ? sv : -1e30f;
#pragma unroll
    for (int off = 32; off >= 1; off >>= 1) m = fmaxf(m, __shfl_xor(m, off));
    float p = valid ? __expf(sv - m) : 0.f;
    float lsum = p;
#pragma unroll
    for (int off = 32; off >= 1; off >>= 1) lsum += __shfl_xor(lsum, off);
    sc[w][lane] = p;   // unnormalized prob, tail zeroed

    // ---- Pass 2: O_part = P.V, 4 pages fully unrolled ----
    // V page layout: [d(128)][tok(16)]. Lane owns dims {2*lane, 2*lane+1}:
    // a contiguous 128B strip per page. Wave covers 8KB contiguous.
    float acc0 = 0.f, acc1 = 0.f;
#pragma unroll
    for (int b = 0; b < 4; ++b) {
        const float4* vp = (const float4*)(vc + ((size_t)blks[b] * KVH + kvh) * (HS * BS)
                                              + (size_t)lane * 32);
        const float4 v0 = vp[0], v1 = vp[1], v2 = vp[2], v3 = vp[3];
        const float4 v4 = vp[4], v5 = vp[5], v6 = vp[6], v7 = vp[7];
        const float4 p0 = *(const float4*)&sc[w][b * BS + 0];
        const float4 p1 = *(const float4*)&sc[w][b * BS + 4];
        const float4 p2 = *(const float4*)&sc[w][b * BS + 8];
        const float4 p3 = *(const float4*)&sc[w][b * BS + 12];
        acc0 += p0.x*v0.x + p0.y*v0.y + p0.z*v0.z + p0.w*v0.w
              + p1.x*v1.x + p1.y*v1.y + p1.z*v1.z + p1.w*v1.w
              + p2.x*v2.x + p2.y*v2.y + p2.z*v2.z + p2.w*v2.w
              + p3.x*v3.x + p3.y*v3.y + p3.z*v3.z + p3.w*v3.w;
        acc1 += p0.x*v4.x + p0.y*v4.y + p0.z*v4.z + p0.w*v4.w
              + p1.x*v5.x + p1.y*v5.y + p1.z*v5.z + p1.w*v5.w
              + p2.x*v6.x + p2.y*v6.y + p2.z*v6.z + p2.w*v6.w
              + p3.x*v7.x + p3.y*v7.y + p3.z*v7.z + p3.w*v7.w;
    }

    const int    idx   = ((seq * KVH + kvh) * PARTS + part) * QPKV + w;
    ((float2*)(o_part + (size_t)idx * HS))[lane] = make_float2(acc0, acc1);
    if (lane == 0) { m_part[idx] = m; l_part[idx] = lsum; }
}

// One WG (128 threads) per (seq, head): merge <=16 partitions.
__launch_bounds__(128)
__global__ void pa_combine(const float* __restrict__ o_part,
                           const float* __restrict__ m_part,
                           const float* __restrict__ l_part,
                           const int*   __restrict__ cl,
                           float*       __restrict__ out)
{
    const int h   = blockIdx.x & (NHEAD - 1);
    const int seq = blockIdx.x >> 5;
    const int kvh = h >> 2;
    const int g   = h & 3;
    const int d   = threadIdx.x;
    const int ctx = cl[seq];
    const int np  = (ctx + PSIZE - 1) / PSIZE;

    const int base = (seq * KVH + kvh) * PARTS * QPKV + g;
    float M = -1e30f;
    for (int p = 0; p < np; ++p)
        M = fmaxf(M, m_part[base + p * QPKV]);
    float L = 0.f, acc = 0.f;
    for (int p = 0; p < np; ++p) {
        const float wgt = __expf(m_part[base + p * QPKV] - M);
        L   += l_part[base + p * QPKV] * wgt;
        acc += wgt * o_part[(size_t)(base + p * QPKV) * HS + d];
    }
    out[((size_t)seq * NHEAD + h) * HS + d] = acc / L;
}

extern "C" void kernel_launch(void* const* d_in, const int* in_sizes, int n_in,
                              void* d_out, int out_size, void* d_ws, size_t ws_size,
                              hipStream_t stream) {
    const float* query        = (const float*)d_in[0];
    const float* key_cache    = (const float*)d_in[1];
    const float* value_cache  = (const float*)d_in[2];
    const int*   block_tables = (const int*)d_in[3];
    const int*   context_lens = (const int*)d_in[4];
    float* out = (float*)d_out;

    float* o_part = (float*)d_ws;
    float* m_part = o_part + O_PART_ELEMS;
    float* l_part = m_part + ML_ELEMS;

    pa_part<<<dim3(NSEQ * KVH * PARTS), dim3(256), 0, stream>>>(
        query, key_cache, value_cache, block_tables, context_lens,
        o_part, m_part, l_part);
    pa_combine<<<dim3(NSEQ * NHEAD), dim3(128), 0, stream>>>(
        o_part, m_part, l_part, context_lens, out);
}